// Round 17
// baseline (137.811 us; speedup 1.0000x reference)
//
#include <hip/hip_runtime.h>
#include <hip/hip_bf16.h>

#define NN 384
#define CC 128
#define PP (NN*NN)      // 147456 positions
#define PB 64           // positions per block
#define NB (PP/PB)      // 2304 blocks
#define TPB 256         // 4 waves; each wave owns one 16-row stripe (16x16x32 MFMA)

typedef __attribute__((ext_vector_type(8))) short bf16x8;
typedef __attribute__((ext_vector_type(4))) float f32x4;
typedef __attribute__((ext_vector_type(8))) unsigned short u16x8;

// 8 weight planes (32KB each) in order:
// 0 AGH, 1 APH, 2 APL, 3 BGH, 4 BPH, 5 BPL, 6 G, 7 Z
// Plane layout (R7/R12-proven): chunk (k0*8+n)*64+l holds
// W[n*16+(l&15)][k0*32+(l>>4)*8 .. +7], k0 in [0,4).

__device__ __forceinline__ unsigned short f2bf(float f){
  __hip_bfloat16 h = __float2bfloat16(f);
  return __builtin_bit_cast(unsigned short, h);
}
__device__ __forceinline__ float bf2f(unsigned h){ return __uint_as_float(h<<16); }
__device__ __forceinline__ unsigned pack2(float a, float b){
  return (unsigned)f2bf(a) | ((unsigned)f2bf(b)<<16);
}
__device__ __forceinline__ float sigmoidf_(float x){
  return __fdividef(1.0f, 1.0f + __expf(-x));
}

// ---------------------------------------------------------------------------
__global__ __launch_bounds__(256) void k0_wprep(
    const float* __restrict__ wap, const float* __restrict__ wag,
    const float* __restrict__ wbp, const float* __restrict__ wbg,
    const float* __restrict__ wg,  const float* __restrict__ wz,
    unsigned short* __restrict__ wfrag){
  int tid = blockIdx.x*256 + threadIdx.x;      // 0..16383
  int plane = tid >> 11, chunk = tid & 2047;
  const float* W = (plane==0) ? wag
                 : (plane==1||plane==2) ? wap
                 : (plane==3) ? wbg
                 : (plane==4||plane==5) ? wbp
                 : (plane==6) ? wg : wz;
  bool lo = (plane==2)||(plane==5);
  int k0 = chunk >> 9, n = (chunk >> 6) & 7, l = chunk & 63;
  int o  = n*16 + (l & 15);
  int kb = k0*32 + ((l>>4)<<3);
  const float* s = W + o*128 + kb;
  u16x8 v;
  #pragma unroll
  for (int e=0;e<8;e++){
    float w = s[e];
    unsigned short hh = f2bf(w);
    v[e] = lo ? f2bf(w - bf2f(hh)) : hh;
  }
  *(u16x8*)(wfrag + (size_t)tid*8) = v;
}

// ---------------------------------------------------------------------------
// Full-plane passes reading weight fragments DIRECTLY from global (L1/L2-hot).
// Per lane: 16B coalesced load at plane + q*8192 + n*1024 + l*16.
// Accumulation order identical to R15 (bit-identical results).
// ---------------------------------------------------------------------------
__device__ __forceinline__ void pass_Hg(const bf16x8* a,
    const unsigned char* __restrict__ wp, int l, f32x4* acc){
  #pragma unroll
  for (int q=0;q<4;q++){
    #pragma unroll
    for (int n=0;n<8;n++){
      bf16x8 f = *(const bf16x8*)(wp + q*8192 + n*1024 + l*16);
      acc[n] = __builtin_amdgcn_mfma_f32_16x16x32_bf16(a[q], f, acc[n], 0,0,0);
    }
  }
}
__device__ __forceinline__ void pass_HLg(const bf16x8* aH, const bf16x8* aL,
    const unsigned char* __restrict__ wp, int l, f32x4* acc){
  #pragma unroll
  for (int q=0;q<4;q++){
    #pragma unroll
    for (int n=0;n<8;n++){
      bf16x8 f = *(const bf16x8*)(wp + q*8192 + n*1024 + l*16);
      acc[n] = __builtin_amdgcn_mfma_f32_16x16x32_bf16(aH[q], f, acc[n], 0,0,0);
      acc[n] = __builtin_amdgcn_mfma_f32_16x16x32_bf16(aL[q], f, acc[n], 0,0,0);
    }
  }
}
__device__ __forceinline__ void bias_init(const float* __restrict__ b, int cb,
                                          f32x4* acc){
  #pragma unroll
  for (int n=0;n<8;n++){
    float v = b[n*16 + cb];
    f32x4 iv = {v,v,v,v};
    acc[n]=iv;
  }
}
// A-frag extraction from [row][col] XOR-swizzled bf16 tile (R7/R12-proven).
__device__ __forceinline__ void extract4(const unsigned char* base, int row0,
                                         int l, bf16x8 a[4]){
  int row = row0 + (l&15);
  int swz = (row&7)<<4;
  #pragma unroll
  for (int k0=0;k0<4;k0++){
    unsigned off = (unsigned)(row*256 + ((((l>>4)<<4) + (k0<<6)) ^ swz));
    a[k0] = *(const bf16x8*)(base + off);
  }
}

// ---------------------------------------------------------------------------
// Fused kernel (R15 numerics VERBATIM; weights read from global, no staging,
// no barriers — everything wave-local). LDS 16KB: buf = zn(H then L) -> xn.
// ---------------------------------------------------------------------------
__global__ __launch_bounds__(TPB,2) void k_fused(
    const float* __restrict__ z, const float* __restrict__ mask,
    const float* __restrict__ bap, const float* __restrict__ bag,
    const float* __restrict__ bbp, const float* __restrict__ bbg,
    const float* __restrict__ bgg, const float* __restrict__ bz,
    const float* __restrict__ lniw, const float* __restrict__ lnib,
    const float* __restrict__ lnow, const float* __restrict__ lnob,
    const unsigned short* __restrict__ wfrag,
    float* __restrict__ out){
  __shared__ unsigned char buf[16384];   // zn -> xn (wave-local 4K regions)
  const unsigned char* wf = (const unsigned char*)wfrag;
  const int t = threadIdx.x;
  const int pos0 = blockIdx.x * PB;
  const int wv = t>>6, l = t&63;
  const int hg = (t>>5)&1;              // 32-lane group within wave
  const int c4 = (t&31)<<2;
  const int row0 = wv*16;

  // ---- P1: LN(z) WAVE-LOCAL (2 rows/iter), znH -> buf, znL packed in regs ----
  unsigned plr[16];
  {
    float4 lw = *(const float4*)(lniw + c4);
    float4 lb = *(const float4*)(lnib + c4);
    #pragma unroll
    for (int it=0; it<8; ++it){
      int row = row0 + it*2 + hg;
      float4 v = *(const float4*)(z + (size_t)(pos0+row)*CC + c4);
      float s = v.x+v.y+v.z+v.w;
      #pragma unroll
      for (int mm=1; mm<32; mm<<=1) s += __shfl_xor(s,mm);
      float mu = s*(1.0f/128.0f);
      float d0=v.x-mu, d1=v.y-mu, d2=v.z-mu, d3=v.w-mu;
      float ss = d0*d0+d1*d1+d2*d2+d3*d3;
      #pragma unroll
      for (int mm=1; mm<32; mm<<=1) ss += __shfl_xor(ss,mm);
      float rstd = rsqrtf(ss*(1.0f/128.0f) + 1e-5f);
      float n0=d0*rstd*lw.x+lb.x, n1=d1*rstd*lw.y+lb.y;
      float n2=d2*rstd*lw.z+lb.z, n3=d3*rstd*lw.w+lb.w;
      unsigned short hh0=f2bf(n0), hh1=f2bf(n1), hh2=f2bf(n2), hh3=f2bf(n3);
      unsigned off = (unsigned)(row*256 + ((c4<<1) ^ ((row&7)<<4)));
      *(uint2*)(buf + off) = make_uint2((unsigned)hh0|((unsigned)hh1<<16),
                                        (unsigned)hh2|((unsigned)hh3<<16));
      plr[it*2]   = pack2(n0-bf2f(hh0), n1-bf2f(hh1));
      plr[it*2+1] = pack2(n2-bf2f(hh2), n3-bf2f(hh3));
    }
  }
  // aH from znH (same-wave ds ordering; R8-proven pattern)
  bf16x8 aH[4], aLo[4];
  extract4(buf, row0, l, aH);
  // overwrite with znL residuals (wave-local), then aLo
  #pragma unroll
  for (int it=0; it<8; ++it){
    int row = row0 + it*2 + hg;
    unsigned off = (unsigned)(row*256 + ((c4<<1) ^ ((row&7)<<4)));
    *(uint2*)(buf + off) = make_uint2(plr[it*2], plr[it*2+1]);
  }
  extract4(buf, row0, l, aLo);

  const int cb = l&15;            // D col-within-16 / A row-within-16
  const int g4 = (l>>4)<<2;       // D row-quad base

  float mk[4];
  #pragma unroll
  for (int r=0;r<4;r++) mk[r] = mask[pos0 + row0 + g4 + r];

  f32x4 gA[8], gB[8], prj[8];     // all-f32 dataflow (R15)

#define SIG_INPLACE(A) do{ \
    _Pragma("unroll") \
    for (int n=0;n<8;n++) \
      _Pragma("unroll") \
      for (int r=0;r<4;r++) (A)[n][r] = sigmoidf_((A)[n][r]); \
  }while(0)

  // ---- a-gate (hi-only) -> gA, sigmoid in place ----
  bias_init(bag,cb,gA); pass_Hg(aH, wf + 0*32768, l, gA);
  SIG_INPLACE(gA);
  // ---- a-proj (f32-grade) -> prj ----
  bias_init(bap,cb,prj);
  pass_HLg(aH, aLo, wf + 1*32768, l, prj);
  pass_Hg (aH,      wf + 2*32768, l, prj);
  // ---- xa = prj*sig(ga)*mask -> keep in gA (registers) ----
  #pragma unroll
  for (int n=0;n<8;n++)
    #pragma unroll
    for (int r=0;r<4;r++)
      gA[n][r] = prj[n][r]*gA[n][r]*mk[r];
  // ---- b-gate (hi-only) -> gB, sigmoid in place ----
  bias_init(bbg,cb,gB); pass_Hg(aH, wf + 3*32768, l, gB);
  SIG_INPLACE(gB);
  // ---- b-proj -> prj ----
  bias_init(bbp,cb,prj);
  pass_HLg(aH, aLo, wf + 4*32768, l, prj);
  pass_Hg (aH,      wf + 5*32768, l, prj);
  // ---- x = xa * (prj*sig(gb)*mask) in gA ; LN(x) ; xn -> buf ; extract a2 ----
  bf16x8 a2[4];
  {
    #pragma unroll
    for (int n=0;n<8;n++)
      #pragma unroll
      for (int r=0;r<4;r++)
        gA[n][r] *= prj[n][r]*gB[n][r]*mk[r];
    float lw8[8], lb8[8];
    #pragma unroll
    for (int n=0;n<8;n++){ lw8[n]=lnow[n*16+cb]; lb8[n]=lnob[n*16+cb]; }
    #pragma unroll
    for (int r=0;r<4;r++){
      float s=0.f;
      #pragma unroll
      for (int n=0;n<8;n++) s += gA[n][r];
      #pragma unroll
      for (int mm=1; mm<16; mm<<=1) s += __shfl_xor(s,mm);
      float mu = s*(1.0f/128.0f);
      float ss=0.f;
      #pragma unroll
      for (int n=0;n<8;n++){ float d = gA[n][r]-mu; ss += d*d; }
      #pragma unroll
      for (int mm=1; mm<16; mm<<=1) ss += __shfl_xor(ss,mm);
      float rstd = rsqrtf(ss*(1.0f/128.0f) + 1e-5f);
      int row = row0 + g4 + r;
      int swz = (row&7)<<4;
      #pragma unroll
      for (int n=0;n<8;n++){
        int colb = (n*16+cb)*2;
        float vvv = (gA[n][r]-mu)*rstd*lw8[n]+lb8[n];
        *(unsigned short*)(buf + row*256 + (colb ^ swz)) = f2bf(vvv);
      }
    }
    extract4(buf, row0, l, a2);   // own rows; same-wave ds ordering
  }
  // ---- g-gate (zn@Wg, hi-only) -> gB, sigmoid ; final proj (xn@Wz) -> prj ----
  bias_init(bgg,cb,gB); pass_Hg(aH, wf + 6*32768, l, gB);
  SIG_INPLACE(gB);
  bias_init(bz,cb,prj); pass_Hg(a2, wf + 7*32768, l, prj);
  // ---- epilogue: out = prj * gB ----
  #pragma unroll
  for (int n=0;n<8;n++){
    #pragma unroll
    for (int r=0;r<4;r++){
      int row = row0 + g4 + r;
      out[(size_t)(pos0+row)*CC + n*16 + cb] = prj[n][r]*gB[n][r];
    }
  }
#undef SIG_INPLACE
}

extern "C" void kernel_launch(void* const* d_in, const int* in_sizes, int n_in,
                              void* d_out, int out_size, void* d_ws, size_t ws_size,
                              hipStream_t stream){
  const float* z     = (const float*)d_in[0];
  const float* mask  = (const float*)d_in[1];
  const float* w_ap  = (const float*)d_in[2];
  const float* b_ap  = (const float*)d_in[3];
  const float* w_bp  = (const float*)d_in[4];
  const float* b_bp  = (const float*)d_in[5];
  const float* w_ag  = (const float*)d_in[6];
  const float* b_ag  = (const float*)d_in[7];
  const float* w_bg  = (const float*)d_in[8];
  const float* b_bg  = (const float*)d_in[9];
  const float* w_g   = (const float*)d_in[10];
  const float* b_g   = (const float*)d_in[11];
  const float* w_z   = (const float*)d_in[12];
  const float* b_z   = (const float*)d_in[13];
  const float* ln_in_w  = (const float*)d_in[14];
  const float* ln_in_b  = (const float*)d_in[15];
  const float* ln_out_w = (const float*)d_in[16];
  const float* ln_out_b = (const float*)d_in[17];

  unsigned short* wfrag = (unsigned short*)d_ws;   // 8 planes * 32KB = 256KB

  k0_wprep<<<64, 256, 0, stream>>>(w_ap, w_ag, w_bp, w_bg, w_g, w_z, wfrag);
  k_fused<<<NB, TPB, 0, stream>>>(z, mask, b_ap, b_ag, b_bp, b_bg, b_g, b_z,
                                  ln_in_w, ln_in_b, ln_out_w, ln_out_b,
                                  wfrag, (float*)d_out);
}

// Round 18
// 114.963 us; speedup vs baseline: 1.1987x; 1.1987x over previous
//
#include <hip/hip_runtime.h>
#include <hip/hip_bf16.h>
#include <hip/hip_fp16.h>

#define NN 384
#define CC 128
#define PP (NN*NN)      // 147456 positions
#define PB 128          // positions per block
#define NB (PP/PB)      // 1152 blocks
#define TPB 256         // 4 waves; each wave owns 32 rows (32x32x16 MFMA)

typedef __attribute__((ext_vector_type(8))) short bf16x8;
typedef __attribute__((ext_vector_type(16))) float f32x16;
typedef __attribute__((ext_vector_type(8))) unsigned short u16x8;

// D-layout for 32x32: row = (reg&3) + 8*(reg>>2) + 4*h, col = lane&31 (m74/m101)
#define ROWT(reg,h) ((((reg)&3) + 8*((reg)>>2)) + 4*(h))

// 8 weight planes (32KB each) in PHASE order:
// 0 AGH, 1 APH, 2 APL, 3 BGH, 4 BPH, 5 BPL, 6 G, 7 Z
// 32x32 fragment layout (R8/R10-proven): chunk (k0*4+n)*64+l holds
// W[n*32+(l&31)][k0*16+(l>>5)*8 .. +7], k0 in [0,8). Half h = k0 in [4h,4h+4).

__device__ __forceinline__ unsigned short f2bf(float f){
  __hip_bfloat16 h = __float2bfloat16(f);
  return __builtin_bit_cast(unsigned short, h);
}
__device__ __forceinline__ float bf2f(unsigned h){ return __uint_as_float(h<<16); }
__device__ __forceinline__ unsigned pack2(float a, float b){
  return (unsigned)f2bf(a) | ((unsigned)f2bf(b)<<16);
}
__device__ __forceinline__ float sigmoidf_(float x){
  return __fdividef(1.0f, 1.0f + __expf(-x));
}
__device__ __forceinline__ unsigned short f2h(float f){
  __half h = __float2half(f);
  return __builtin_bit_cast(unsigned short, h);
}
__device__ __forceinline__ float h2f(unsigned short u){
  __half h = __builtin_bit_cast(__half, u);
  return __half2float(h);
}
__device__ __forceinline__ unsigned pack2h(float a, float b){
  return (unsigned)f2h(a) | ((unsigned)f2h(b)<<16);
}

// ---------------------------------------------------------------------------
__global__ __launch_bounds__(256) void k0_wprep(
    const float* __restrict__ wap, const float* __restrict__ wag,
    const float* __restrict__ wbp, const float* __restrict__ wbg,
    const float* __restrict__ wg,  const float* __restrict__ wz,
    unsigned short* __restrict__ wfrag){
  int tid = blockIdx.x*256 + threadIdx.x;      // 0..16383
  int plane = tid >> 11, chunk = tid & 2047;
  const float* W = (plane==0) ? wag
                 : (plane==1||plane==2) ? wap
                 : (plane==3) ? wbg
                 : (plane==4||plane==5) ? wbp
                 : (plane==6) ? wg : wz;
  bool lo = (plane==2)||(plane==5);
  int k0 = chunk >> 8, n = (chunk >> 6) & 3, l = chunk & 63;
  int o  = n*32 + (l & 31);
  int kb = k0*16 + ((l>>5)<<3);
  const float* s = W + o*128 + kb;
  u16x8 v;
  #pragma unroll
  for (int e=0;e<8;e++){
    float w = s[e];
    unsigned short hh = f2bf(w);
    v[e] = lo ? f2bf(w - bf2f(hh)) : hh;
  }
  *(u16x8*)(wfrag + (size_t)tid*8) = v;
}

// ---------------------------------------------------------------------------
// Stage one 16KB half-plane into a slot via global_load_lds (R10-proven).
// ---------------------------------------------------------------------------
__device__ __forceinline__ void stage_half(const unsigned char* __restrict__ src_base,
                                           unsigned char* slot, int t){
  int wv = t>>6, l = t&63;
  const unsigned char* src = src_base + wv*4096 + l*16;
  unsigned char* dst = slot + wv*4096;
  #pragma unroll
  for (int i=0;i<4;i++)
    __builtin_amdgcn_global_load_lds(
        (const __attribute__((address_space(1))) unsigned int*)(src + i*1024),
        (__attribute__((address_space(3))) unsigned int*)(dst + i*1024),
        16, 0, 0);
}

// ---------------------------------------------------------------------------
// Half-plane passes: 4 k-steps x 4 n (R10's pass_H16/pass_HL16 verbatim).
// ---------------------------------------------------------------------------
__device__ __forceinline__ void pass_H(const bf16x8* a, int kbase,
    const unsigned char* slot, int l, f32x16* acc){
  #pragma unroll
  for (int kr=0;kr<4;kr++){
    #pragma unroll
    for (int n=0;n<4;n++){
      bf16x8 f = *(const bf16x8*)(slot + (kr*4+n)*1024 + l*16);
      acc[n] = __builtin_amdgcn_mfma_f32_32x32x16_bf16(a[kbase+kr], f, acc[n],0,0,0);
    }
  }
}
__device__ __forceinline__ void pass_HL(const bf16x8* aH, const bf16x8* aL, int kbase,
    const unsigned char* slot, int l, f32x16* acc){
  #pragma unroll
  for (int kr=0;kr<4;kr++){
    #pragma unroll
    for (int n=0;n<4;n++){
      bf16x8 f = *(const bf16x8*)(slot + (kr*4+n)*1024 + l*16);
      acc[n] = __builtin_amdgcn_mfma_f32_32x32x16_bf16(aH[kbase+kr], f, acc[n],0,0,0);
      acc[n] = __builtin_amdgcn_mfma_f32_32x32x16_bf16(aL[kbase+kr], f, acc[n],0,0,0);
    }
  }
}
__device__ __forceinline__ void bias_init32(const float* __restrict__ b, int c,
                                            f32x16* acc){
  #pragma unroll
  for (int n=0;n<4;n++){
    float v = b[n*32+c];
    #pragma unroll
    for (int r=0;r<16;r++) acc[n][r]=v;
  }
}
// A-frag extraction from [row][col] XOR-swizzled bf16 tile (R8-proven).
__device__ __forceinline__ void extract8(const unsigned char* R0, int row, int h,
                                         bf16x8 a[8]){
  int swz = (row&7)<<4;
  #pragma unroll
  for (int k0=0;k0<8;k0++){
    unsigned off = (unsigned)(row*256 + (((k0<<5) + (h<<4)) ^ swz));
    a[k0] = *(const bf16x8*)(R0 + off);
  }
}

// ---------------------------------------------------------------------------
// Fused kernel: M=32/wave, 16 half-plane phases, 2-slot stage-1-ahead.
// LDS 64KB: buf[0,32K) zn(H then L)->xa->xn (wave-local 8K rows regions);
//           slots [32K,48K),[48K,64K).
// Numerics = R13 (hi/lo proj, hi-only f16 gates, bf16 xa park, f32 LN).
// ---------------------------------------------------------------------------
__global__ __launch_bounds__(TPB,2) void k_fused(
    const float* __restrict__ z, const float* __restrict__ mask,
    const float* __restrict__ bap, const float* __restrict__ bag,
    const float* __restrict__ bbp, const float* __restrict__ bbg,
    const float* __restrict__ bgg, const float* __restrict__ bz,
    const float* __restrict__ lniw, const float* __restrict__ lnib,
    const float* __restrict__ lnow, const float* __restrict__ lnob,
    const unsigned short* __restrict__ wfrag,
    float* __restrict__ out){
  __shared__ unsigned char lds[65536];
  unsigned char* buf = lds;             // 32KB: zn -> xa -> xn
  const unsigned char* wfrag8 = (const unsigned char*)wfrag;
  const int t = threadIdx.x;
  const int pos0 = blockIdx.x * PB;
  const int wv = t>>6, l = t&63;
  const int h = l>>5, c = l&31;
  const int c4 = c<<2;
  const int row0 = wv*32;

  // prologue: stage half 0 (AGH h0) -> slot 0
  stage_half(wfrag8, lds + 32768, t);

  // ---- P1: LN(z) WAVE-LOCAL (2 rows/iter, 16 iters), znH -> buf, znL in regs ----
  unsigned plr[32];
  {
    float4 lw = *(const float4*)(lniw + c4);
    float4 lb = *(const float4*)(lnib + c4);
    #pragma unroll
    for (int it=0; it<16; ++it){
      int row = row0 + it*2 + h;
      float4 v = *(const float4*)(z + (size_t)(pos0+row)*CC + c4);
      float s = v.x+v.y+v.z+v.w;
      #pragma unroll
      for (int mm=1; mm<32; mm<<=1) s += __shfl_xor(s,mm);
      float mu = s*(1.0f/128.0f);
      float d0=v.x-mu, d1=v.y-mu, d2=v.z-mu, d3=v.w-mu;
      float ss = d0*d0+d1*d1+d2*d2+d3*d3;
      #pragma unroll
      for (int mm=1; mm<32; mm<<=1) ss += __shfl_xor(ss,mm);
      float rstd = rsqrtf(ss*(1.0f/128.0f) + 1e-5f);
      float n0=d0*rstd*lw.x+lb.x, n1=d1*rstd*lw.y+lb.y;
      float n2=d2*rstd*lw.z+lb.z, n3=d3*rstd*lw.w+lb.w;
      unsigned short hh0=f2bf(n0), hh1=f2bf(n1), hh2=f2bf(n2), hh3=f2bf(n3);
      unsigned off = (unsigned)(row*256 + ((c4<<1) ^ ((row&7)<<4)));
      *(uint2*)(buf + off) = make_uint2((unsigned)hh0|((unsigned)hh1<<16),
                                        (unsigned)hh2|((unsigned)hh3<<16));
      plr[it*2]   = pack2(n0-bf2f(hh0), n1-bf2f(hh1));
      plr[it*2+1] = pack2(n2-bf2f(hh2), n3-bf2f(hh3));
    }
  }
  // aH from znH; overwrite with znL; aLo  (fence-free wave-local, R13-proven)
  bf16x8 aH[8], aLo[8];
  extract8(buf, row0+c, h, aH);
  #pragma unroll
  for (int it=0; it<16; ++it){
    int row = row0 + it*2 + h;
    unsigned off = (unsigned)(row*256 + ((c4<<1) ^ ((row&7)<<4)));
    *(uint2*)(buf + off) = make_uint2(plr[it*2], plr[it*2+1]);
  }
  extract8(buf, row0+c, h, aLo);

  float mkr[16];
  #pragma unroll
  for (int reg=0;reg<16;reg++) mkr[reg] = mask[pos0 + row0 + ROWT(reg,h)];

  f32x16 acc[4];
  unsigned gpk[32];     // packed f16 gate (64 values/lane)

#define SL(p) (lds + 32768 + (((p)&1)<<14))
#define PH(p) do{ __syncthreads(); \
    if ((p)+1 < 16) stage_half(wfrag8 + (((size_t)((p)+1))<<14), SL((p)+1), t); }while(0)
#define PACK_GATE() do{ \
    _Pragma("unroll") \
    for (int n=0;n<4;n++) \
      _Pragma("unroll") \
      for (int rp=0;rp<8;rp++) \
        gpk[n*8+rp] = pack2h(sigmoidf_(acc[n][2*rp]), sigmoidf_(acc[n][2*rp+1])); \
  }while(0)

  // ---- a-gate (hi-only) -> pack f16 ----
  PH(0);  bias_init32(bag,c,acc); pass_H(aH,0,SL(0), l,acc);
  PH(1);  pass_H(aH,4,SL(1), l,acc);
  PACK_GATE();
  // ---- a-proj (f32-grade hi/lo) ----
  PH(2);  bias_init32(bap,c,acc); pass_HL(aH,aLo,0,SL(2), l,acc);
  PH(3);  pass_HL(aH,aLo,4,SL(3), l,acc);
  PH(4);  pass_H(aH,0,SL(4), l,acc);      // APL h0
  PH(5);  pass_H(aH,4,SL(5), l,acc);      // APL h1
  // ---- xa = a*sig(ga)*mask -> park bf16 frag-order in own buf region ----
  {
    unsigned char* xr = buf + wv*8192;
    #pragma unroll
    for (int n=0;n<4;n++){
      #pragma unroll
      for (int j=0;j<8;j++){
        float g0 = h2f((unsigned short)(gpk[n*8+j] & 0xffffu));
        float g1 = h2f((unsigned short)(gpk[n*8+j] >> 16));
        float a0 = acc[n][2*j]  *g0*mkr[2*j];
        float a1 = acc[n][2*j+1]*g1*mkr[2*j+1];
        *(unsigned*)(xr + (n*8+j)*256 + l*4) = pack2(a0,a1);
      }
    }
  }
  // ---- b-gate (hi-only) -> pack f16 ----
  PH(6);  bias_init32(bbg,c,acc); pass_H(aH,0,SL(6), l,acc);
  PH(7);  pass_H(aH,4,SL(7), l,acc);
  PACK_GATE();
  // ---- b-proj (f32-grade hi/lo) ----
  PH(8);  bias_init32(bbp,c,acc); pass_HL(aH,aLo,0,SL(8), l,acc);
  PH(9);  pass_HL(aH,aLo,4,SL(9), l,acc);     // last aLo use
  PH(10); pass_H(aH,0,SL(10),l,acc);          // BPL h0
  PH(11); pass_H(aH,4,SL(11),l,acc);          // BPL h1
  // ---- x = xa*b ; LN(x) in-register ; xn -> buf ; extract a2 (wave-local) ----
  bf16x8 a2[8];
  {
    f32x16 xv[4];
    const unsigned char* xr = buf + wv*8192;
    #pragma unroll
    for (int n=0;n<4;n++){
      #pragma unroll
      for (int j=0;j<8;j++){
        float g0 = h2f((unsigned short)(gpk[n*8+j] & 0xffffu));
        float g1 = h2f((unsigned short)(gpk[n*8+j] >> 16));
        unsigned w = *(const unsigned*)(xr + (n*8+j)*256 + l*4);
        float b0 = acc[n][2*j]  *g0*mkr[2*j];
        float b1 = acc[n][2*j+1]*g1*mkr[2*j+1];
        xv[n][2*j]   = bf2f(w & 0xffffu)*b0;
        xv[n][2*j+1] = bf2f(w >> 16)   *b1;
      }
    }
    float lw4[4], lb4[4];
    #pragma unroll
    for (int n=0;n<4;n++){ lw4[n]=lnow[n*32+c]; lb4[n]=lnob[n*32+c]; }
    #pragma unroll
    for (int reg=0; reg<16; ++reg){
      float s=0.f;
      #pragma unroll
      for (int n=0;n<4;n++) s += xv[n][reg];
      #pragma unroll
      for (int mm=1; mm<32; mm<<=1) s += __shfl_xor(s,mm);
      float mu = s*(1.0f/128.0f);
      float ss=0.f;
      #pragma unroll
      for (int n=0;n<4;n++){ float d=xv[n][reg]-mu; ss+=d*d; }
      #pragma unroll
      for (int mm=1; mm<32; mm<<=1) ss += __shfl_xor(ss,mm);
      float rstd = rsqrtf(ss*(1.0f/128.0f)+1e-5f);
      int row = row0 + ROWT(reg,h);
      int swz = (row&7)<<4;
      #pragma unroll
      for (int n=0;n<4;n++){
        int colb = (n*32+c)*2;
        float vvv = (xv[n][reg]-mu)*rstd*lw4[n]+lb4[n];
        *(unsigned short*)(buf + row*256 + (colb ^ swz)) = f2bf(vvv);
      }
    }
    extract8(buf, row0+c, h, a2);   // own rows; same-wave ds ordering
  }
  // ---- g-gate (zn@Wg, hi-only) -> pack ; final proj (xn@Wz) ----
  PH(12); bias_init32(bgg,c,acc); pass_H(aH,0,SL(12),l,acc);
  PH(13); pass_H(aH,4,SL(13),l,acc);
  PACK_GATE();
  PH(14); bias_init32(bz,c,acc); pass_H(a2,0,SL(14),l,acc);
  PH(15); pass_H(a2,4,SL(15),l,acc);
  // ---- epilogue: out = o * sig(gv) ----
  #pragma unroll
  for (int n=0;n<4;n++){
    #pragma unroll
    for (int reg=0; reg<16; ++reg){
      int row = row0 + ROWT(reg,h);
      float gg = h2f((unsigned short)((gpk[n*8+(reg>>1)] >> ((reg&1)*16)) & 0xffffu));
      out[(size_t)(pos0+row)*CC + n*32 + c] = acc[n][reg]*gg;
    }
  }
#undef PH
#undef SL
#undef PACK_GATE
}

extern "C" void kernel_launch(void* const* d_in, const int* in_sizes, int n_in,
                              void* d_out, int out_size, void* d_ws, size_t ws_size,
                              hipStream_t stream){
  const float* z     = (const float*)d_in[0];
  const float* mask  = (const float*)d_in[1];
  const float* w_ap  = (const float*)d_in[2];
  const float* b_ap  = (const float*)d_in[3];
  const float* w_bp  = (const float*)d_in[4];
  const float* b_bp  = (const float*)d_in[5];
  const float* w_ag  = (const float*)d_in[6];
  const float* b_ag  = (const float*)d_in[7];
  const float* w_bg  = (const float*)d_in[8];
  const float* b_bg  = (const float*)d_in[9];
  const float* w_g   = (const float*)d_in[10];
  const float* b_g   = (const float*)d_in[11];
  const float* w_z   = (const float*)d_in[12];
  const float* b_z   = (const float*)d_in[13];
  const float* ln_in_w  = (const float*)d_in[14];
  const float* ln_in_b  = (const float*)d_in[15];
  const float* ln_out_w = (const float*)d_in[16];
  const float* ln_out_b = (const float*)d_in[17];

  unsigned short* wfrag = (unsigned short*)d_ws;   // 8 planes * 32KB = 256KB

  k0_wprep<<<64, 256, 0, stream>>>(w_ap, w_ag, w_bp, w_bg, w_g, w_z, wfrag);
  k_fused<<<NB, TPB, 0, stream>>>(z, mask, b_ap, b_ag, b_bp, b_bg, b_g, b_z,
                                  ln_in_w, ln_in_b, ln_out_w, ln_out_b,
                                  wfrag, (float*)d_out);
}

// Round 19
// 102.040 us; speedup vs baseline: 1.3506x; 1.1266x over previous
//
#include <hip/hip_runtime.h>
#include <hip/hip_bf16.h>
#include <hip/hip_fp16.h>

#define NN 384
#define CC 128
#define PP (NN*NN)      // 147456 positions
#define PB 64           // positions per block
#define NB (PP/PB)      // 2304 blocks
#define TPB 256         // 4 waves; each wave owns one 16-row stripe (16x16x32 MFMA)

typedef __attribute__((ext_vector_type(8))) short bf16x8;
typedef __attribute__((ext_vector_type(4))) float f32x4;
typedef __attribute__((ext_vector_type(8))) unsigned short u16x8;

// 8 weight planes (32KB each) in PHASE order:
// 0 AGH, 1 APH, 2 APL, 3 BGH, 4 BPH, 5 BPL, 6 G, 7 Z
// Plane layout (R7/R12-proven): chunk (k0*8+n)*64+l holds
// W[n*16+(l&15)][k0*32+(l>>4)*8 .. +7], k0 in [0,4).
// Eighth e of a plane = chunks (k0*8+n) with k0=e>>1, n in [(e&1)*4,(e&1)*4+4)
// = bytes [e*4096, e*4096+4096) (contiguous).

__device__ __forceinline__ unsigned short f2bf(float f){
  __hip_bfloat16 h = __float2bfloat16(f);
  return __builtin_bit_cast(unsigned short, h);
}
__device__ __forceinline__ float bf2f(unsigned h){ return __uint_as_float(h<<16); }
__device__ __forceinline__ unsigned pack2(float a, float b){
  return (unsigned)f2bf(a) | ((unsigned)f2bf(b)<<16);
}
__device__ __forceinline__ float sigmoidf_(float x){
  return __fdividef(1.0f, 1.0f + __expf(-x));
}
__device__ __forceinline__ unsigned short f2h(float f){
  __half h = __float2half(f);
  return __builtin_bit_cast(unsigned short, h);
}
__device__ __forceinline__ float h2f(unsigned short u){
  __half h = __builtin_bit_cast(__half, u);
  return __half2float(h);
}

// ---------------------------------------------------------------------------
__global__ __launch_bounds__(256) void k0_wprep(
    const float* __restrict__ wap, const float* __restrict__ wag,
    const float* __restrict__ wbp, const float* __restrict__ wbg,
    const float* __restrict__ wg,  const float* __restrict__ wz,
    unsigned short* __restrict__ wfrag){
  int tid = blockIdx.x*256 + threadIdx.x;      // 0..16383
  int plane = tid >> 11, chunk = tid & 2047;
  const float* W = (plane==0) ? wag
                 : (plane==1||plane==2) ? wap
                 : (plane==3) ? wbg
                 : (plane==4||plane==5) ? wbp
                 : (plane==6) ? wg : wz;
  bool lo = (plane==2)||(plane==5);
  int k0 = chunk >> 9, n = (chunk >> 6) & 7, l = chunk & 63;
  int o  = n*16 + (l & 15);
  int kb = k0*32 + ((l>>4)<<3);
  const float* s = W + o*128 + kb;
  u16x8 v;
  #pragma unroll
  for (int e=0;e<8;e++){
    float w = s[e];
    unsigned short hh = f2bf(w);
    v[e] = lo ? f2bf(w - bf2f(hh)) : hh;
  }
  *(u16x8*)(wfrag + (size_t)tid*8) = v;
}

// ---------------------------------------------------------------------------
// Stage one 4KB plane-eighth into a slot: ONE global_load_lds per thread.
// ---------------------------------------------------------------------------
__device__ __forceinline__ void stage_e(const unsigned char* __restrict__ src_base,
                                        unsigned char* slot, int t){
  int wv = t>>6, l = t&63;
  __builtin_amdgcn_global_load_lds(
      (const __attribute__((address_space(1))) unsigned int*)(src_base + wv*1024 + l*16),
      (__attribute__((address_space(3))) unsigned int*)(slot + wv*1024),
      16, 0, 0);
}

// ---------------------------------------------------------------------------
// Eighth passes: 1 k-step x 4 n. Slot offset n'*1024 + l*16 (n' = n-nb local).
// A-frag: row=row0+(l&15), k=k0*32+(l>>4)*8+e. D: row=row0+(l>>4)*4+r, col=n*16+(l&15).
// HL variant extracts the aLo fragment TRANSIENTLY from bufL (znL tile).
// ---------------------------------------------------------------------------
__device__ __forceinline__ void pass8_H(const bf16x8* a, int k0, int nb,
    const unsigned char* slot, int l, f32x4* acc){
  #pragma unroll
  for (int n=0;n<4;n++){
    bf16x8 f = *(const bf16x8*)(slot + n*1024 + l*16);
    acc[nb+n] = __builtin_amdgcn_mfma_f32_16x16x32_bf16(a[k0], f, acc[nb+n], 0,0,0);
  }
}
__device__ __forceinline__ void pass8_HL(const bf16x8* aH,
    const unsigned char* bufL, int row0, int k0, int nb,
    const unsigned char* slot, int l, f32x4* acc){
  int row = row0 + (l&15);
  int swz = (row&7)<<4;
  bf16x8 aLoq = *(const bf16x8*)(bufL + row*256 + ((((l>>4)<<4) + (k0<<6)) ^ swz));
  #pragma unroll
  for (int n=0;n<4;n++){
    bf16x8 f = *(const bf16x8*)(slot + n*1024 + l*16);
    acc[nb+n] = __builtin_amdgcn_mfma_f32_16x16x32_bf16(aH[k0], f, acc[nb+n], 0,0,0);
    acc[nb+n] = __builtin_amdgcn_mfma_f32_16x16x32_bf16(aLoq,   f, acc[nb+n], 0,0,0);
  }
}
__device__ __forceinline__ void bias_init(const float* __restrict__ b, int cb,
                                          f32x4* acc){
  #pragma unroll
  for (int n=0;n<8;n++){
    float v = b[n*16 + cb];
    f32x4 iv = {v,v,v,v};
    acc[n]=iv;
  }
}
// A-frag extraction from [row][col] XOR-swizzled bf16 tile (R7/R12-proven).
__device__ __forceinline__ void extract4(const unsigned char* base, int row0,
                                         int l, bf16x8 a[4]){
  int row = row0 + (l&15);
  int swz = (row&7)<<4;
  #pragma unroll
  for (int k0=0;k0<4;k0++){
    unsigned off = (unsigned)(row*256 + ((((l>>4)<<4) + (k0<<6)) ^ swz));
    a[k0] = *(const bf16x8*)(base + off);
  }
}

// ---------------------------------------------------------------------------
// Fused kernel: 64 eighth-phases, 2-slot rotation, stage-1-ahead.
// LDS 40KB: bufH[0,16K) znH->xa ; bufL[16K,32K) znL->xn ; slots [32K,40K).
// Reg diet for 4 waves/SIMD: single acc(32 AGPR) + aH(16) + gpk(16);
// znL residuals live in LDS (aLo fragments extracted transiently).
// ---------------------------------------------------------------------------
__global__ __launch_bounds__(TPB,4) void k_fused(
    const float* __restrict__ z, const float* __restrict__ mask,
    const float* __restrict__ bap, const float* __restrict__ bag,
    const float* __restrict__ bbp, const float* __restrict__ bbg,
    const float* __restrict__ bgg, const float* __restrict__ bz,
    const float* __restrict__ lniw, const float* __restrict__ lnib,
    const float* __restrict__ lnow, const float* __restrict__ lnob,
    const unsigned short* __restrict__ wfrag,
    float* __restrict__ out){
  __shared__ unsigned char lds[40960];
  unsigned char* bufH = lds;            // 16KB: znH -> xa (wave-local regions)
  unsigned char* bufL = lds + 16384;    // 16KB: znL -> xn
  const unsigned char* wfrag8 = (const unsigned char*)wfrag;
  const int t = threadIdx.x;
  const int pos0 = blockIdx.x * PB;
  const int wv = t>>6, l = t&63;
  const int hg = (t>>5)&1;              // 32-lane group within wave
  const int c4 = (t&31)<<2;
  const int row0 = wv*16;

  // prologue: stage eighth 0 (AGH e0) -> slot 0
  stage_e(wfrag8, lds + 32768, t);

  // ---- P1: LN(z) WAVE-LOCAL (2 rows/iter); znH -> bufH, znL -> bufL ----
  {
    float4 lw = *(const float4*)(lniw + c4);
    float4 lb = *(const float4*)(lnib + c4);
    #pragma unroll
    for (int it=0; it<8; ++it){
      int row = row0 + it*2 + hg;
      float4 v = *(const float4*)(z + (size_t)(pos0+row)*CC + c4);
      float s = v.x+v.y+v.z+v.w;
      #pragma unroll
      for (int mm=1; mm<32; mm<<=1) s += __shfl_xor(s,mm);
      float mu = s*(1.0f/128.0f);
      float d0=v.x-mu, d1=v.y-mu, d2=v.z-mu, d3=v.w-mu;
      float ss = d0*d0+d1*d1+d2*d2+d3*d3;
      #pragma unroll
      for (int mm=1; mm<32; mm<<=1) ss += __shfl_xor(ss,mm);
      float rstd = rsqrtf(ss*(1.0f/128.0f) + 1e-5f);
      float n0=d0*rstd*lw.x+lb.x, n1=d1*rstd*lw.y+lb.y;
      float n2=d2*rstd*lw.z+lb.z, n3=d3*rstd*lw.w+lb.w;
      unsigned short hh0=f2bf(n0), hh1=f2bf(n1), hh2=f2bf(n2), hh3=f2bf(n3);
      unsigned off = (unsigned)(row*256 + ((c4<<1) ^ ((row&7)<<4)));
      *(uint2*)(bufH + off) = make_uint2((unsigned)hh0|((unsigned)hh1<<16),
                                         (unsigned)hh2|((unsigned)hh3<<16));
      *(uint2*)(bufL + off) = make_uint2(pack2(n0-bf2f(hh0), n1-bf2f(hh1)),
                                         pack2(n2-bf2f(hh2), n3-bf2f(hh3)));
    }
  }
  // aH from znH (same-wave ds ordering; R8-proven pattern)
  bf16x8 aH[4];
  extract4(bufH, row0, l, aH);

  const int cb = l&15;            // D col-within-16 / A row-within-16
  const int g4 = (l>>4)<<2;       // D row-quad base

  float mk[4];
  #pragma unroll
  for (int r=0;r<4;r++) mk[r] = mask[pos0 + row0 + g4 + r];

  f32x4 acc[8];
  unsigned gpk[16];     // packed f16 gate (32 values)

#define SL(p) (lds + 32768 + (((p)&1)<<12))
#define PH(p) do{ __syncthreads(); \
    if ((p)+1 < 64) stage_e(wfrag8 + (((size_t)((p)+1))<<12), SL((p)+1), t); }while(0)
#define PACK_GATE() do{ \
    _Pragma("unroll") \
    for (int n=0;n<8;n++) \
      _Pragma("unroll") \
      for (int rp=0;rp<2;rp++) \
        gpk[n*2+rp] = (unsigned)f2h(sigmoidf_(acc[n][2*rp])) \
                    | ((unsigned)f2h(sigmoidf_(acc[n][2*rp+1]))<<16); \
  }while(0)

  // ---- a-gate (AGH, hi-only), pack f16 ----
  bias_init(bag,cb,acc);
  #pragma unroll
  for (int e=0;e<8;e++){ PH(e); pass8_H(aH, e>>1, (e&1)*4, SL(e), l, acc); }
  PACK_GATE();
  // ---- a-proj: (aH+aLo)@APH + aH@APL ----
  bias_init(bap,cb,acc);
  #pragma unroll
  for (int e=0;e<8;e++){ PH(8+e); pass8_HL(aH, bufL, row0, e>>1, (e&1)*4, SL(8+e), l, acc); }
  #pragma unroll
  for (int e=0;e<8;e++){ PH(16+e); pass8_H(aH, e>>1, (e&1)*4, SL(16+e), l, acc); }
  // ---- xa = a*sig(ga)*mask -> park bf16 pair-order in own bufH region ----
  {
    unsigned char* xr = bufH + wv*4096;
    #pragma unroll
    for (int n=0;n<8;n++){
      #pragma unroll
      for (int rp=0;rp<2;rp++){
        float g0 = h2f((unsigned short)(gpk[n*2+rp] & 0xffffu));
        float g1 = h2f((unsigned short)(gpk[n*2+rp] >> 16));
        float a0 = acc[n][2*rp]  *g0*mk[2*rp];
        float a1 = acc[n][2*rp+1]*g1*mk[2*rp+1];
        *(unsigned*)(xr + (n*2+rp)*256 + l*4) = pack2(a0,a1);
      }
    }
  }
  // ---- b-gate (BGH, hi-only), pack ----
  bias_init(bbg,cb,acc);
  #pragma unroll
  for (int e=0;e<8;e++){ PH(24+e); pass8_H(aH, e>>1, (e&1)*4, SL(24+e), l, acc); }
  PACK_GATE();
  // ---- b-proj: (aH+aLo)@BPH + aH@BPL ----
  bias_init(bbp,cb,acc);
  #pragma unroll
  for (int e=0;e<8;e++){ PH(32+e); pass8_HL(aH, bufL, row0, e>>1, (e&1)*4, SL(32+e), l, acc); }
  #pragma unroll
  for (int e=0;e<8;e++){ PH(40+e); pass8_H(aH, e>>1, (e&1)*4, SL(40+e), l, acc); }
  // ---- x = xa*b ; LN(x) in-register ; xn -> bufL ; extract a2 (wave-local) ----
  bf16x8 a2[4];
  {
    f32x4 xv[8];
    const unsigned char* xr = bufH + wv*4096;
    #pragma unroll
    for (int n=0;n<8;n++){
      #pragma unroll
      for (int rp=0;rp<2;rp++){
        float g0 = h2f((unsigned short)(gpk[n*2+rp] & 0xffffu));
        float g1 = h2f((unsigned short)(gpk[n*2+rp] >> 16));
        unsigned w = *(const unsigned*)(xr + (n*2+rp)*256 + l*4);
        float b0 = acc[n][2*rp]  *g0*mk[2*rp];
        float b1 = acc[n][2*rp+1]*g1*mk[2*rp+1];
        xv[n][2*rp]   = bf2f(w & 0xffffu)*b0;
        xv[n][2*rp+1] = bf2f(w >> 16)   *b1;
      }
    }
    float lw8[8], lb8[8];
    #pragma unroll
    for (int n=0;n<8;n++){ lw8[n]=lnow[n*16+cb]; lb8[n]=lnob[n*16+cb]; }
    #pragma unroll
    for (int r=0;r<4;r++){
      float s=0.f;
      #pragma unroll
      for (int n=0;n<8;n++) s += xv[n][r];
      #pragma unroll
      for (int mm=1; mm<16; mm<<=1) s += __shfl_xor(s,mm);
      float mu = s*(1.0f/128.0f);
      float ss=0.f;
      #pragma unroll
      for (int n=0;n<8;n++){ float d = xv[n][r]-mu; ss += d*d; }
      #pragma unroll
      for (int mm=1; mm<16; mm<<=1) ss += __shfl_xor(ss,mm);
      float rstd = rsqrtf(ss*(1.0f/128.0f) + 1e-5f);
      int row = row0 + g4 + r;
      int swz = (row&7)<<4;
      #pragma unroll
      for (int n=0;n<8;n++){
        int colb = (n*16+cb)*2;
        float vvv = (xv[n][r]-mu)*rstd*lw8[n]+lb8[n];
        *(unsigned short*)(bufL + row*256 + (colb ^ swz)) = f2bf(vvv);
      }
    }
    extract4(bufL, row0, l, a2);   // own rows; same-wave ds ordering
  }
  // ---- g-gate (G, hi-only) -> pack ; final proj (Z, xn@Wz) ----
  bias_init(bgg,cb,acc);
  #pragma unroll
  for (int e=0;e<8;e++){ PH(48+e); pass8_H(aH, e>>1, (e&1)*4, SL(48+e), l, acc); }
  PACK_GATE();
  bias_init(bz,cb,acc);
  #pragma unroll
  for (int e=0;e<8;e++){ PH(56+e); pass8_H(a2, e>>1, (e&1)*4, SL(56+e), l, acc); }
  // ---- epilogue: out = o * sig(gv) ----
  #pragma unroll
  for (int n=0;n<8;n++){
    #pragma unroll
    for (int r=0;r<4;r++){
      int row = row0 + g4 + r;
      float gg = h2f((unsigned short)((gpk[n*2+(r>>1)] >> ((r&1)*16)) & 0xffffu));
      out[(size_t)(pos0+row)*CC + n*16 + cb] = acc[n][r]*gg;
    }
  }
#undef PH
#undef SL
#undef PACK_GATE
}

extern "C" void kernel_launch(void* const* d_in, const int* in_sizes, int n_in,
                              void* d_out, int out_size, void* d_ws, size_t ws_size,
                              hipStream_t stream){
  const float* z     = (const float*)d_in[0];
  const float* mask  = (const float*)d_in[1];
  const float* w_ap  = (const float*)d_in[2];
  const float* b_ap  = (const float*)d_in[3];
  const float* w_bp  = (const float*)d_in[4];
  const float* b_bp  = (const float*)d_in[5];
  const float* w_ag  = (const float*)d_in[6];
  const float* b_ag  = (const float*)d_in[7];
  const float* w_bg  = (const float*)d_in[8];
  const float* b_bg  = (const float*)d_in[9];
  const float* w_g   = (const float*)d_in[10];
  const float* b_g   = (const float*)d_in[11];
  const float* w_z   = (const float*)d_in[12];
  const float* b_z   = (const float*)d_in[13];
  const float* ln_in_w  = (const float*)d_in[14];
  const float* ln_in_b  = (const float*)d_in[15];
  const float* ln_out_w = (const float*)d_in[16];
  const float* ln_out_b = (const float*)d_in[17];

  unsigned short* wfrag = (unsigned short*)d_ws;   // 8 planes * 32KB = 256KB

  k0_wprep<<<64, 256, 0, stream>>>(w_ap, w_ag, w_bp, w_bg, w_g, w_z, wfrag);
  k_fused<<<NB, TPB, 0, stream>>>(z, mask, b_ap, b_ag, b_bp, b_bg, b_g, b_z,
                                  ln_in_w, ln_in_b, ln_out_w, ln_out_b,
                                  wfrag, (float*)d_out);
}